// Round 10
// baseline (253.421 us; speedup 1.0000x reference)
//
#include <hip/hip_runtime.h>
#include <hip/hip_bf16.h>

#define D 128
#define RPB 256            // rows per bucket (8-bit in-bucket row)
#define RPB_SHIFT 8
#define NBMAX 512          // max buckets (bscan single block of 512)
#define P1CHUNK 8192       // edges per pass1/bhist block
#define P2CAP 15360        // staged edges per bucket (120 KB LDS)
#define NKEY 4096          // 256 rows x 16 col-tiles (col >> 13)

using bf16x8 = __attribute__((ext_vector_type(8))) short;
using f32x4  = __attribute__((ext_vector_type(4))) float;
using f32x2  = __attribute__((ext_vector_type(2))) float;

static __device__ inline unsigned short f2bf(float f) {
    __hip_bfloat16 b = __float2bfloat16(f);
    return reinterpret_cast<unsigned short&>(b);
}

// ---------------- Kernel A: h = x @ W^T + bias via MFMA bf16 (proven R3) ----
__global__ __launch_bounds__(256) void gemm_mfma_kernel(
    const float* __restrict__ x, const float* __restrict__ W,
    const float* __restrict__ bias, __hip_bfloat16* __restrict__ h, int N)
{
    __shared__ unsigned short sA[128 * 128];
    __shared__ unsigned short sB[128 * 128];

    const int tid   = threadIdx.x;
    const int nbase = blockIdx.x * 128;

#pragma unroll
    for (int it = 0; it < 16; ++it) {
        const int r = it * 8 + (tid >> 5);
        const int c = (tid & 31) * 4;
        const unsigned addr = (unsigned)((r * 256 + c * 2) ^ ((r & 7) << 4));

        const int gr = nbase + r;
        float4 xv = make_float4(0.f, 0.f, 0.f, 0.f);
        if (gr < N) xv = *reinterpret_cast<const float4*>(x + (size_t)gr * D + c);
        ushort4 xb = make_ushort4(f2bf(xv.x), f2bf(xv.y), f2bf(xv.z), f2bf(xv.w));
        *reinterpret_cast<ushort4*>(reinterpret_cast<char*>(sA) + addr) = xb;

        float4 wv = *reinterpret_cast<const float4*>(W + (size_t)r * D + c);
        ushort4 wb = make_ushort4(f2bf(wv.x), f2bf(wv.y), f2bf(wv.z), f2bf(wv.w));
        *reinterpret_cast<ushort4*>(reinterpret_cast<char*>(sB) + addr) = wb;
    }
    __syncthreads();

    const int wid  = tid >> 6;
    const int lane = tid & 63;
    const int wr   = (wid >> 1) * 64;
    const int wc   = (wid & 1) * 64;
    const int lrow = lane & 15;
    const int lkb  = (lane >> 4) * 16;

    f32x4 acc[4][4] = {};

#pragma unroll
    for (int kk = 0; kk < 4; ++kk) {
        const int kbyte = kk * 64 + lkb;
        bf16x8 a[4], b[4];
#pragma unroll
        for (int m = 0; m < 4; ++m) {
            const int row = wr + m * 16 + lrow;
            const unsigned addr = (unsigned)((row * 256 + kbyte) ^ ((row & 7) << 4));
            a[m] = *reinterpret_cast<const bf16x8*>(reinterpret_cast<const char*>(sA) + addr);
        }
#pragma unroll
        for (int n = 0; n < 4; ++n) {
            const int row = wc + n * 16 + lrow;
            const unsigned addr = (unsigned)((row * 256 + kbyte) ^ ((row & 7) << 4));
            b[n] = *reinterpret_cast<const bf16x8*>(reinterpret_cast<const char*>(sB) + addr);
        }
#pragma unroll
        for (int m = 0; m < 4; ++m)
#pragma unroll
            for (int n = 0; n < 4; ++n)
                acc[m][n] = __builtin_amdgcn_mfma_f32_16x16x32_bf16(a[m], b[n], acc[m][n], 0, 0, 0);
    }

    float bv[4];
#pragma unroll
    for (int n = 0; n < 4; ++n) bv[n] = bias[wc + n * 16 + lrow];

#pragma unroll
    for (int m = 0; m < 4; ++m) {
        const int row0 = nbase + wr + m * 16 + (lane >> 4) * 4;
#pragma unroll
        for (int n = 0; n < 4; ++n) {
            const int col = wc + n * 16 + lrow;
#pragma unroll
            for (int r = 0; r < 4; ++r) {
                const int grow = row0 + r;
                if (grow < N)
                    h[(size_t)grow * D + col] = __float2bfloat16(acc[m][n][r] + bv[n]);
            }
        }
    }
}

// ---------------- bucket histogram (LDS-aggregated, int4 reads) -------------
__global__ __launch_bounds__(256) void bhist_kernel(
    const int* __restrict__ rows, int* __restrict__ bcount, int E)
{
    __shared__ int lh[NBMAX];
    const int tid = threadIdx.x;
    for (int i = tid; i < NBMAX; i += 256) lh[i] = 0;
    __syncthreads();
    const int base = blockIdx.x * P1CHUNK;
#pragma unroll
    for (int it = 0; it < P1CHUNK / 1024; ++it) {
        int e = base + (it * 256 + tid) * 4;
        if (e + 3 < E) {
            int4 r4 = *reinterpret_cast<const int4*>(rows + e);
            atomicAdd(&lh[r4.x >> RPB_SHIFT], 1);
            atomicAdd(&lh[r4.y >> RPB_SHIFT], 1);
            atomicAdd(&lh[r4.z >> RPB_SHIFT], 1);
            atomicAdd(&lh[r4.w >> RPB_SHIFT], 1);
        } else {
            for (int k = 0; k < 4; ++k)
                if (e + k < E) atomicAdd(&lh[rows[e + k] >> RPB_SHIFT], 1);
        }
    }
    __syncthreads();
    for (int i = tid; i < NBMAX; i += 256) {
        int c = lh[i];
        if (c) atomicAdd(&bcount[i], c);
    }
}

// ---------------- bucket exclusive scan (1 block, NB <= 512) ----------------
__global__ __launch_bounds__(512) void bscan_kernel(
    const int* __restrict__ bcount, int* __restrict__ bstart,
    int* __restrict__ bcur, int NB, int E)
{
    __shared__ int s[512];
    const int tid = threadIdx.x;
    int v = (tid < NB) ? bcount[tid] : 0;
    s[tid] = v;
    __syncthreads();
    for (int off = 1; off < 512; off <<= 1) {
        int t = (tid >= off) ? s[tid - off] : 0;
        __syncthreads();
        s[tid] += t;
        __syncthreads();
    }
    if (tid < NB) {
        int excl = s[tid] - v;
        bstart[tid] = excl;
        bcur[tid]   = excl;
    }
    if (tid == 0) bstart[NB] = E;
}

// ---------------- pass1: partition edges into buckets (contiguous runs) -----
// packed = (row_in_bucket << 17) | col   (col < 2^17)
__global__ __launch_bounds__(256) void pass1_kernel(
    const int* __restrict__ rows, const int* __restrict__ cols,
    const float* __restrict__ vals, int* __restrict__ bcur,
    uint2* __restrict__ pairs, int E)
{
    __shared__ int srows[P1CHUNK];   // 32 KB
    __shared__ int lh[NBMAX];
    __shared__ int lbase[NBMAX];

    const int tid  = threadIdx.x;
    const int base = blockIdx.x * P1CHUNK;

    for (int i = tid; i < NBMAX; i += 256) lh[i] = 0;
    __syncthreads();

#pragma unroll 4
    for (int it = 0; it < P1CHUNK / 256; ++it) {
        int e = base + it * 256 + tid;
        int r = (e < E) ? rows[e] : -1;
        srows[it * 256 + tid] = r;
        if (r >= 0) atomicAdd(&lh[r >> RPB_SHIFT], 1);
    }
    __syncthreads();

    for (int i = tid; i < NBMAX; i += 256) {
        int c = lh[i];
        lbase[i] = c ? atomicAdd(&bcur[i], c) : 0;
        lh[i] = 0;
    }
    __syncthreads();

#pragma unroll 4
    for (int it = 0; it < P1CHUNK / 256; ++it) {
        int e = base + it * 256 + tid;
        int r = srows[it * 256 + tid];
        if (r < 0) continue;
        int b = r >> RPB_SHIFT;
        int lofs = atomicAdd(&lh[b], 1);
        unsigned packed = ((unsigned)(r & (RPB - 1)) << 17) | (unsigned)cols[e];
        pairs[lbase[b] + lofs] = make_uint2(packed, __float_as_uint(vals[e]));
    }
}

// ---------------- pass2: counting sort by (row, col-tile) + CSR rowstart ----
// Key = packed >> 13 = row(8b) * 16 + col>>13 (4b): 4096 bins. Within each
// row, edges come out ascending by 8K-col tile -> gather sweeps h in order,
// keeping the hot h window (~2 MB) L2-resident across all in-flight waves.
__global__ __launch_bounds__(256) void pass2_kernel(
    uint2* __restrict__ pairs, const int* __restrict__ bstart,
    int* __restrict__ rowstart, int N)
{
    __shared__ uint2 st[P2CAP];   // 120 KB
    __shared__ int rh[NKEY];      // 16 KB: hist -> absolute starts -> cursors
    __shared__ int sc[256];       // 1 KB

    const int b   = blockIdx.x;
    const int tid = threadIdx.x;
    const int start = bstart[b];
    const int end   = bstart[b + 1];
    int cnt = end - start;
    if (cnt > P2CAP) cnt = P2CAP;

    for (int i = tid; i < NKEY; i += 256) rh[i] = 0;
    __syncthreads();

    // stage + histogram of 12-bit keys
    for (int i = tid; i < cnt; i += 256) {
        uint2 p = pairs[start + i];
        st[i] = p;
        atomicAdd(&rh[p.x >> 13], 1);
    }
    __syncthreads();

    // hierarchical exclusive scan over 4096 bins -> absolute start positions
    int loc[16];
    int sum = 0;
    const int base16 = tid * 16;
#pragma unroll
    for (int k = 0; k < 16; ++k) { loc[k] = rh[base16 + k]; sum += loc[k]; }
    sc[tid] = sum;
    __syncthreads();
    for (int off = 1; off < 256; off <<= 1) {
        int t = (tid >= off) ? sc[tid - off] : 0;
        __syncthreads();
        sc[tid] += t;
        __syncthreads();
    }
    int pre = start + sc[tid] - sum;
#pragma unroll
    for (int k = 0; k < 16; ++k) { rh[base16 + k] = pre; pre += loc[k]; }
    __syncthreads();

    // CSR rowstart = start of key (row << 4); must read rh before scatter mutates
    int grow = b * RPB + tid;
    if (grow < N) rowstart[grow] = rh[tid << 4];
    __syncthreads();

    // scatter sorted (rh doubles as cursors)
    for (int i = tid; i < cnt; i += 256) {
        uint2 p = st[i];
        int pos = atomicAdd(&rh[p.x >> 13], 1);
        pairs[pos] = make_uint2(p.x & 0x1FFFFu, p.y);
    }
}

// ---------------- row gather: out[r] = sum v * h_bf[c] ----------------------
// One wave per row; 16 independent h-gathers in flight, then 8, then scalar.
// nt ONLY on the final out store (dead store).
__global__ __launch_bounds__(256) void row_gather_kernel(
    const __hip_bfloat16* __restrict__ hbf, const uint2* __restrict__ pairs,
    const int* __restrict__ rowstart, float* __restrict__ out, int N, int E)
{
    int row  = (int)((blockIdx.x * (size_t)blockDim.x + threadIdx.x) >> 6);
    int lane = threadIdx.x & 63;
    if (row >= N) return;

    int start = rowstart[row];
    int end   = (row + 1 < N) ? rowstart[row + 1] : E;

    const unsigned short* hb = reinterpret_cast<const unsigned short*>(hbf);
    float ax = 0.0f, ay = 0.0f;

    int e = start;
    const int end16 = e + ((end - e) & ~15);
    for (; e < end16; e += 16) {
        uint2 cv[16];
        unsigned hv[16];
#pragma unroll
        for (int u = 0; u < 16; ++u) cv[u] = pairs[e + u];
#pragma unroll
        for (int u = 0; u < 16; ++u)
            hv[u] = *reinterpret_cast<const unsigned*>(hb + (size_t)cv[u].x * D + lane * 2);
#pragma unroll
        for (int u = 0; u < 16; ++u) {
            float v = __uint_as_float(cv[u].y);
            ax += v * __uint_as_float(hv[u] << 16);
            ay += v * __uint_as_float(hv[u] & 0xffff0000u);
        }
    }
    const int end8 = e + ((end - e) & ~7);
    for (; e < end8; e += 8) {
        uint2 cv[8];
        unsigned hv[8];
#pragma unroll
        for (int u = 0; u < 8; ++u) cv[u] = pairs[e + u];
#pragma unroll
        for (int u = 0; u < 8; ++u)
            hv[u] = *reinterpret_cast<const unsigned*>(hb + (size_t)cv[u].x * D + lane * 2);
#pragma unroll
        for (int u = 0; u < 8; ++u) {
            float v = __uint_as_float(cv[u].y);
            ax += v * __uint_as_float(hv[u] << 16);
            ay += v * __uint_as_float(hv[u] & 0xffff0000u);
        }
    }
    for (; e < end; ++e) {
        uint2 cv = pairs[e];
        unsigned hv = *reinterpret_cast<const unsigned*>(hb + (size_t)cv.x * D + lane * 2);
        float v = __uint_as_float(cv.y);
        ax += v * __uint_as_float(hv << 16);
        ay += v * __uint_as_float(hv & 0xffff0000u);
    }

    f32x2 r2 = { ax, ay };
    __builtin_nontemporal_store(r2, reinterpret_cast<f32x2*>(out + (size_t)row * D) + lane);
}

// ---------------- fallback path (R1 proven): f32 GEMM + atomic scatter ------
__global__ __launch_bounds__(256) void gemm_kernel(
    const float* __restrict__ x, const float* __restrict__ W,
    const float* __restrict__ bias, float* __restrict__ h, int N)
{
    __shared__ float sWt[D][D];
    __shared__ float sx[16][D];
    const int tid = threadIdx.x;
    for (int idx = tid; idx < D * D; idx += 256) {
        int o = idx >> 7, i = idx & (D - 1);
        sWt[i][o] = W[idx];
    }
    const int nbase = blockIdx.x * 16;
    for (int idx = tid; idx < 16 * D; idx += 256) {
        int r = idx >> 7, i = idx & (D - 1);
        int n = nbase + r;
        sx[r][i] = (n < N) ? x[(size_t)n * D + i] : 0.0f;
    }
    __syncthreads();
    const int c = tid & (D - 1);
    const int rg = tid >> 7;
    float acc[8];
#pragma unroll
    for (int k = 0; k < 8; ++k) acc[k] = 0.0f;
#pragma unroll 4
    for (int i = 0; i < D; ++i) {
        float w = sWt[i][c];
#pragma unroll
        for (int k = 0; k < 8; ++k) acc[k] += sx[rg * 8 + k][i] * w;
    }
    const float b = bias[c];
#pragma unroll
    for (int k = 0; k < 8; ++k) {
        int n = nbase + rg * 8 + k;
        if (n < N) h[(size_t)n * D + c] = acc[k] + b;
    }
}

__global__ __launch_bounds__(256) void scatter_kernel(
    const float* __restrict__ h, const float* __restrict__ vals,
    const int* __restrict__ rows, const int* __restrict__ cols,
    float* __restrict__ out, int E)
{
    const int wid  = (int)((blockIdx.x * (size_t)blockDim.x + threadIdx.x) >> 6);
    const int lane = threadIdx.x & 63;
    if (wid >= E) return;
    const int   r = rows[wid];
    const int   c = cols[wid];
    const float v = vals[wid];
    float2 hv = *reinterpret_cast<const float2*>(h + (size_t)c * D + lane * 2);
    atomicAdd(out + (size_t)r * D + lane * 2,     v * hv.x);
    atomicAdd(out + (size_t)r * D + lane * 2 + 1, v * hv.y);
}

// ---------------- launch ----------------
static inline size_t align16(size_t x) { return (x + 15) & ~(size_t)15; }

extern "C" void kernel_launch(void* const* d_in, const int* in_sizes, int n_in,
                              void* d_out, int out_size, void* d_ws, size_t ws_size,
                              hipStream_t stream)
{
    const float* x    = (const float*)d_in[0];
    const float* W    = (const float*)d_in[1];
    const float* bias = (const float*)d_in[2];
    const float* vals = (const float*)d_in[3];
    const int*   rows = (const int*)d_in[4];
    const int*   cols = (const int*)d_in[5];

    const int N = in_sizes[0] / D;
    const int E = in_sizes[3];
    float* out = (float*)d_out;

    const int NB = (N + RPB - 1) / RPB;

    size_t off_h        = 0;
    size_t off_pairs    = off_h        + align16((size_t)N * D * 2);
    size_t off_rowstart = off_pairs    + align16((size_t)E * 8);
    size_t off_bstart   = off_rowstart + align16((size_t)(N + 1) * 4);
    size_t off_bcount   = off_bstart   + align16((size_t)(NB + 1) * 4);
    size_t off_bcur     = off_bcount   + align16((size_t)NB * 4);
    size_t need         = off_bcur     + align16((size_t)NB * 4);

    if (ws_size >= need && NB <= NBMAX && N <= (1 << 17)) {
        char* ws = (char*)d_ws;
        __hip_bfloat16* hbf = (__hip_bfloat16*)(ws + off_h);
        uint2* pairs        = (uint2*)(ws + off_pairs);
        int*   rowstart     = (int*)(ws + off_rowstart);
        int*   bstart       = (int*)(ws + off_bstart);
        int*   bcount       = (int*)(ws + off_bcount);
        int*   bcur         = (int*)(ws + off_bcur);

        gemm_mfma_kernel<<<(N + 127) / 128, 256, 0, stream>>>(x, W, bias, hbf, N);

        hipMemsetAsync(bcount, 0, (size_t)NB * 4, stream);
        int p1blocks = (E + P1CHUNK - 1) / P1CHUNK;
        bhist_kernel<<<p1blocks, 256, 0, stream>>>(rows, bcount, E);
        bscan_kernel<<<1, 512, 0, stream>>>(bcount, bstart, bcur, NB, E);
        pass1_kernel<<<p1blocks, 256, 0, stream>>>(rows, cols, vals, bcur, pairs, E);
        pass2_kernel<<<NB, 256, 0, stream>>>(pairs, bstart, rowstart, N);

        int gblocks = (int)(((size_t)N * 64 + 255) / 256);
        row_gather_kernel<<<gblocks, 256, 0, stream>>>(hbf, pairs, rowstart, out, N, E);
    } else {
        float* h = (float*)d_ws;
        hipMemsetAsync(out, 0, (size_t)out_size * sizeof(float), stream);
        gemm_kernel<<<(N + 15) / 16, 256, 0, stream>>>(x, W, bias, h, N);
        scatter_kernel<<<(E + 3) / 4, 256, 0, stream>>>(h, vals, rows, cols, out, E);
    }
}

// Round 11
// 235.307 us; speedup vs baseline: 1.0770x; 1.0770x over previous
//
#include <hip/hip_runtime.h>
#include <hip/hip_bf16.h>

#define D 128
#define RPB 256            // rows per bucket (8-bit in-bucket row)
#define RPB_SHIFT 8
#define NBMAX 512          // max buckets (bscan single block of 512)
#define P1CHUNK 8192       // edges per pass1/bhist block
#define P2CAP 15360        // staged edges per bucket (120 KB LDS)

using bf16x8 = __attribute__((ext_vector_type(8))) short;
using f32x4  = __attribute__((ext_vector_type(4))) float;
using f32x2  = __attribute__((ext_vector_type(2))) float;

static __device__ inline unsigned short f2bf(float f) {
    __hip_bfloat16 b = __float2bfloat16(f);
    return reinterpret_cast<unsigned short&>(b);
}

// ---------------- Kernel A: h = x @ W^T + bias via MFMA bf16 (proven R3) ----
__global__ __launch_bounds__(256) void gemm_mfma_kernel(
    const float* __restrict__ x, const float* __restrict__ W,
    const float* __restrict__ bias, __hip_bfloat16* __restrict__ h, int N)
{
    __shared__ unsigned short sA[128 * 128];
    __shared__ unsigned short sB[128 * 128];

    const int tid   = threadIdx.x;
    const int nbase = blockIdx.x * 128;

#pragma unroll
    for (int it = 0; it < 16; ++it) {
        const int r = it * 8 + (tid >> 5);
        const int c = (tid & 31) * 4;
        const unsigned addr = (unsigned)((r * 256 + c * 2) ^ ((r & 7) << 4));

        const int gr = nbase + r;
        float4 xv = make_float4(0.f, 0.f, 0.f, 0.f);
        if (gr < N) xv = *reinterpret_cast<const float4*>(x + (size_t)gr * D + c);
        ushort4 xb = make_ushort4(f2bf(xv.x), f2bf(xv.y), f2bf(xv.z), f2bf(xv.w));
        *reinterpret_cast<ushort4*>(reinterpret_cast<char*>(sA) + addr) = xb;

        float4 wv = *reinterpret_cast<const float4*>(W + (size_t)r * D + c);
        ushort4 wb = make_ushort4(f2bf(wv.x), f2bf(wv.y), f2bf(wv.z), f2bf(wv.w));
        *reinterpret_cast<ushort4*>(reinterpret_cast<char*>(sB) + addr) = wb;
    }
    __syncthreads();

    const int wid  = tid >> 6;
    const int lane = tid & 63;
    const int wr   = (wid >> 1) * 64;
    const int wc   = (wid & 1) * 64;
    const int lrow = lane & 15;
    const int lkb  = (lane >> 4) * 16;

    f32x4 acc[4][4] = {};

#pragma unroll
    for (int kk = 0; kk < 4; ++kk) {
        const int kbyte = kk * 64 + lkb;
        bf16x8 a[4], b[4];
#pragma unroll
        for (int m = 0; m < 4; ++m) {
            const int row = wr + m * 16 + lrow;
            const unsigned addr = (unsigned)((row * 256 + kbyte) ^ ((row & 7) << 4));
            a[m] = *reinterpret_cast<const bf16x8*>(reinterpret_cast<const char*>(sA) + addr);
        }
#pragma unroll
        for (int n = 0; n < 4; ++n) {
            const int row = wc + n * 16 + lrow;
            const unsigned addr = (unsigned)((row * 256 + kbyte) ^ ((row & 7) << 4));
            b[n] = *reinterpret_cast<const bf16x8*>(reinterpret_cast<const char*>(sB) + addr);
        }
#pragma unroll
        for (int m = 0; m < 4; ++m)
#pragma unroll
            for (int n = 0; n < 4; ++n)
                acc[m][n] = __builtin_amdgcn_mfma_f32_16x16x32_bf16(a[m], b[n], acc[m][n], 0, 0, 0);
    }

    float bv[4];
#pragma unroll
    for (int n = 0; n < 4; ++n) bv[n] = bias[wc + n * 16 + lrow];

#pragma unroll
    for (int m = 0; m < 4; ++m) {
        const int row0 = nbase + wr + m * 16 + (lane >> 4) * 4;
#pragma unroll
        for (int n = 0; n < 4; ++n) {
            const int col = wc + n * 16 + lrow;
#pragma unroll
            for (int r = 0; r < 4; ++r) {
                const int grow = row0 + r;
                if (grow < N)
                    h[(size_t)grow * D + col] = __float2bfloat16(acc[m][n][r] + bv[n]);
            }
        }
    }
}

// ---------------- bucket histogram (LDS-aggregated, int4 reads) -------------
__global__ __launch_bounds__(256) void bhist_kernel(
    const int* __restrict__ rows, int* __restrict__ bcount, int E)
{
    __shared__ int lh[NBMAX];
    const int tid = threadIdx.x;
    for (int i = tid; i < NBMAX; i += 256) lh[i] = 0;
    __syncthreads();
    const int base = blockIdx.x * P1CHUNK;
#pragma unroll
    for (int it = 0; it < P1CHUNK / 1024; ++it) {
        int e = base + (it * 256 + tid) * 4;
        if (e + 3 < E) {
            int4 r4 = *reinterpret_cast<const int4*>(rows + e);
            atomicAdd(&lh[r4.x >> RPB_SHIFT], 1);
            atomicAdd(&lh[r4.y >> RPB_SHIFT], 1);
            atomicAdd(&lh[r4.z >> RPB_SHIFT], 1);
            atomicAdd(&lh[r4.w >> RPB_SHIFT], 1);
        } else {
            for (int k = 0; k < 4; ++k)
                if (e + k < E) atomicAdd(&lh[rows[e + k] >> RPB_SHIFT], 1);
        }
    }
    __syncthreads();
    for (int i = tid; i < NBMAX; i += 256) {
        int c = lh[i];
        if (c) atomicAdd(&bcount[i], c);
    }
}

// ---------------- bucket exclusive scan (1 block, NB <= 512) ----------------
__global__ __launch_bounds__(512) void bscan_kernel(
    const int* __restrict__ bcount, int* __restrict__ bstart,
    int* __restrict__ bcur, int NB, int E)
{
    __shared__ int s[512];
    const int tid = threadIdx.x;
    int v = (tid < NB) ? bcount[tid] : 0;
    s[tid] = v;
    __syncthreads();
    for (int off = 1; off < 512; off <<= 1) {
        int t = (tid >= off) ? s[tid - off] : 0;
        __syncthreads();
        s[tid] += t;
        __syncthreads();
    }
    if (tid < NB) {
        int excl = s[tid] - v;
        bstart[tid] = excl;
        bcur[tid]   = excl;
    }
    if (tid == 0) bstart[NB] = E;
}

// ---------------- pass1: partition edges into buckets (contiguous runs) -----
// packed = (row_in_bucket << 17) | col   (col < 2^17)
__global__ __launch_bounds__(256) void pass1_kernel(
    const int* __restrict__ rows, const int* __restrict__ cols,
    const float* __restrict__ vals, int* __restrict__ bcur,
    uint2* __restrict__ pairs, int E)
{
    __shared__ int srows[P1CHUNK];   // 32 KB
    __shared__ int lh[NBMAX];
    __shared__ int lbase[NBMAX];

    const int tid  = threadIdx.x;
    const int base = blockIdx.x * P1CHUNK;

    for (int i = tid; i < NBMAX; i += 256) lh[i] = 0;
    __syncthreads();

#pragma unroll 4
    for (int it = 0; it < P1CHUNK / 256; ++it) {
        int e = base + it * 256 + tid;
        int r = (e < E) ? rows[e] : -1;
        srows[it * 256 + tid] = r;
        if (r >= 0) atomicAdd(&lh[r >> RPB_SHIFT], 1);
    }
    __syncthreads();

    for (int i = tid; i < NBMAX; i += 256) {
        int c = lh[i];
        lbase[i] = c ? atomicAdd(&bcur[i], c) : 0;
        lh[i] = 0;
    }
    __syncthreads();

#pragma unroll 4
    for (int it = 0; it < P1CHUNK / 256; ++it) {
        int e = base + it * 256 + tid;
        int r = srows[it * 256 + tid];
        if (r < 0) continue;
        int b = r >> RPB_SHIFT;
        int lofs = atomicAdd(&lh[b], 1);
        unsigned packed = ((unsigned)(r & (RPB - 1)) << 17) | (unsigned)cols[e];
        pairs[lbase[b] + lofs] = make_uint2(packed, __float_as_uint(vals[e]));
    }
}

// ---------------- pass2: in-place sort within bucket + CSR rowstart ---------
__global__ __launch_bounds__(256) void pass2_kernel(
    uint2* __restrict__ pairs, const int* __restrict__ bstart,
    int* __restrict__ rowstart, int N)
{
    __shared__ uint2 st[P2CAP];   // 120 KB
    __shared__ int rh[RPB];
    __shared__ int sc[RPB];
    __shared__ int cur[RPB];

    const int b   = blockIdx.x;
    const int tid = threadIdx.x;
    const int start = bstart[b];
    const int end   = bstart[b + 1];
    int cnt = end - start;
    if (cnt > P2CAP) cnt = P2CAP;

    rh[tid] = 0;
    __syncthreads();

    for (int i = tid; i < cnt; i += 256) {
        uint2 p = pairs[start + i];
        st[i] = p;
        atomicAdd(&rh[p.x >> 17], 1);
    }
    __syncthreads();

    int myc = rh[tid];
    sc[tid] = myc;
    __syncthreads();
    for (int off = 1; off < 256; off <<= 1) {
        int t = (tid >= off) ? sc[tid - off] : 0;
        __syncthreads();
        sc[tid] += t;
        __syncthreads();
    }
    int excl = sc[tid] - myc;
    cur[tid] = start + excl;
    int grow = b * RPB + tid;
    if (grow < N) rowstart[grow] = start + excl;
    __syncthreads();

    for (int i = tid; i < cnt; i += 256) {
        uint2 p = st[i];
        int r = (int)(p.x >> 17);
        int pos = atomicAdd(&cur[r], 1);
        pairs[pos] = make_uint2(p.x & 0x1FFFFu, p.y);
    }
}

// ---------------- row gather: out[r] = sum v * h_bf[c] ----------------------
// One wave per row. ONE coalesced pairs load covers 64 edges (lane l holds
// pairs[e0+l]); readlane broadcasts each edge's (col,val) to SGPRs, so the
// h load is SGPR-base + constant lane offset: ~0 per-edge address VALU and
// ~1 VMEM per edge. Guard-free batches of 16/8 keep h loads in flight.
__global__ __launch_bounds__(256) void row_gather_kernel(
    const __hip_bfloat16* __restrict__ hbf, const uint2* __restrict__ pairs,
    const int* __restrict__ rowstart, float* __restrict__ out, int N, int E)
{
    int row  = (int)((blockIdx.x * (size_t)blockDim.x + threadIdx.x) >> 6);
    int lane = threadIdx.x & 63;
    if (row >= N) return;

    int start = rowstart[row];
    int end   = (row + 1 < N) ? rowstart[row + 1] : E;

    const char* hb = reinterpret_cast<const char*>(hbf);
    const unsigned lbyte = (unsigned)lane << 2;   // byte offset within h row
    float ax = 0.f, ay = 0.f;

    for (int e0 = start; e0 < end; e0 += 64) {
        int pl = e0 + lane;
        if (pl >= end) pl = end - 1;              // end > e0 >= 0 here
        uint2 p = pairs[pl];                      // 1 coalesced load = 64 edges
        int pc = (int)p.x, pv = (int)p.y;
        int m = end - e0; if (m > 64) m = 64;

        int idx = 0;
        const int m16 = m & ~15;
        for (; idx < m16; idx += 16) {
            unsigned c[16], vb[16], hv[16];
#pragma unroll
            for (int u = 0; u < 16; ++u) {
                c[u]  = (unsigned)__builtin_amdgcn_readlane(pc, idx + u);
                vb[u] = (unsigned)__builtin_amdgcn_readlane(pv, idx + u);
            }
#pragma unroll
            for (int u = 0; u < 16; ++u)
                hv[u] = *reinterpret_cast<const unsigned*>(hb + (((size_t)c[u]) << 8) + lbyte);
#pragma unroll
            for (int u = 0; u < 16; ++u) {
                float v = __uint_as_float(vb[u]);
                ax += v * __uint_as_float(hv[u] << 16);
                ay += v * __uint_as_float(hv[u] & 0xffff0000u);
            }
        }
        const int m8 = m & ~7;
        for (; idx < m8; idx += 8) {
            unsigned c[8], vb[8], hv[8];
#pragma unroll
            for (int u = 0; u < 8; ++u) {
                c[u]  = (unsigned)__builtin_amdgcn_readlane(pc, idx + u);
                vb[u] = (unsigned)__builtin_amdgcn_readlane(pv, idx + u);
            }
#pragma unroll
            for (int u = 0; u < 8; ++u)
                hv[u] = *reinterpret_cast<const unsigned*>(hb + (((size_t)c[u]) << 8) + lbyte);
#pragma unroll
            for (int u = 0; u < 8; ++u) {
                float v = __uint_as_float(vb[u]);
                ax += v * __uint_as_float(hv[u] << 16);
                ay += v * __uint_as_float(hv[u] & 0xffff0000u);
            }
        }
        for (; idx < m; ++idx) {
            unsigned c  = (unsigned)__builtin_amdgcn_readlane(pc, idx);
            unsigned vb = (unsigned)__builtin_amdgcn_readlane(pv, idx);
            unsigned hv = *reinterpret_cast<const unsigned*>(hb + (((size_t)c) << 8) + lbyte);
            float v = __uint_as_float(vb);
            ax += v * __uint_as_float(hv << 16);
            ay += v * __uint_as_float(hv & 0xffff0000u);
        }
    }

    f32x2 r2 = { ax, ay };
    __builtin_nontemporal_store(r2, reinterpret_cast<f32x2*>(out + (size_t)row * D) + lane);
}

// ---------------- fallback path (R1 proven): f32 GEMM + atomic scatter ------
__global__ __launch_bounds__(256) void gemm_kernel(
    const float* __restrict__ x, const float* __restrict__ W,
    const float* __restrict__ bias, float* __restrict__ h, int N)
{
    __shared__ float sWt[D][D];
    __shared__ float sx[16][D];
    const int tid = threadIdx.x;
    for (int idx = tid; idx < D * D; idx += 256) {
        int o = idx >> 7, i = idx & (D - 1);
        sWt[i][o] = W[idx];
    }
    const int nbase = blockIdx.x * 16;
    for (int idx = tid; idx < 16 * D; idx += 256) {
        int r = idx >> 7, i = idx & (D - 1);
        int n = nbase + r;
        sx[r][i] = (n < N) ? x[(size_t)n * D + i] : 0.0f;
    }
    __syncthreads();
    const int c = tid & (D - 1);
    const int rg = tid >> 7;
    float acc[8];
#pragma unroll
    for (int k = 0; k < 8; ++k) acc[k] = 0.0f;
#pragma unroll 4
    for (int i = 0; i < D; ++i) {
        float w = sWt[i][c];
#pragma unroll
        for (int k = 0; k < 8; ++k) acc[k] += sx[rg * 8 + k][i] * w;
    }
    const float b = bias[c];
#pragma unroll
    for (int k = 0; k < 8; ++k) {
        int n = nbase + rg * 8 + k;
        if (n < N) h[(size_t)n * D + c] = acc[k] + b;
    }
}

__global__ __launch_bounds__(256) void scatter_kernel(
    const float* __restrict__ h, const float* __restrict__ vals,
    const int* __restrict__ rows, const int* __restrict__ cols,
    float* __restrict__ out, int E)
{
    const int wid  = (int)((blockIdx.x * (size_t)blockDim.x + threadIdx.x) >> 6);
    const int lane = threadIdx.x & 63;
    if (wid >= E) return;
    const int   r = rows[wid];
    const int   c = cols[wid];
    const float v = vals[wid];
    float2 hv = *reinterpret_cast<const float2*>(h + (size_t)c * D + lane * 2);
    atomicAdd(out + (size_t)r * D + lane * 2,     v * hv.x);
    atomicAdd(out + (size_t)r * D + lane * 2 + 1, v * hv.y);
}

// ---------------- launch ----------------
static inline size_t align16(size_t x) { return (x + 15) & ~(size_t)15; }

extern "C" void kernel_launch(void* const* d_in, const int* in_sizes, int n_in,
                              void* d_out, int out_size, void* d_ws, size_t ws_size,
                              hipStream_t stream)
{
    const float* x    = (const float*)d_in[0];
    const float* W    = (const float*)d_in[1];
    const float* bias = (const float*)d_in[2];
    const float* vals = (const float*)d_in[3];
    const int*   rows = (const int*)d_in[4];
    const int*   cols = (const int*)d_in[5];

    const int N = in_sizes[0] / D;
    const int E = in_sizes[3];
    float* out = (float*)d_out;

    const int NB = (N + RPB - 1) / RPB;

    size_t off_h        = 0;
    size_t off_pairs    = off_h        + align16((size_t)N * D * 2);
    size_t off_rowstart = off_pairs    + align16((size_t)E * 8);
    size_t off_bstart   = off_rowstart + align16((size_t)(N + 1) * 4);
    size_t off_bcount   = off_bstart   + align16((size_t)(NB + 1) * 4);
    size_t off_bcur     = off_bcount   + align16((size_t)NB * 4);
    size_t need         = off_bcur     + align16((size_t)NB * 4);

    if (ws_size >= need && NB <= NBMAX && N <= (1 << 17)) {
        char* ws = (char*)d_ws;
        __hip_bfloat16* hbf = (__hip_bfloat16*)(ws + off_h);
        uint2* pairs        = (uint2*)(ws + off_pairs);
        int*   rowstart     = (int*)(ws + off_rowstart);
        int*   bstart       = (int*)(ws + off_bstart);
        int*   bcount       = (int*)(ws + off_bcount);
        int*   bcur         = (int*)(ws + off_bcur);

        gemm_mfma_kernel<<<(N + 127) / 128, 256, 0, stream>>>(x, W, bias, hbf, N);

        hipMemsetAsync(bcount, 0, (size_t)NB * 4, stream);
        int p1blocks = (E + P1CHUNK - 1) / P1CHUNK;
        bhist_kernel<<<p1blocks, 256, 0, stream>>>(rows, bcount, E);
        bscan_kernel<<<1, 512, 0, stream>>>(bcount, bstart, bcur, NB, E);
        pass1_kernel<<<p1blocks, 256, 0, stream>>>(rows, cols, vals, bcur, pairs, E);
        pass2_kernel<<<NB, 256, 0, stream>>>(pairs, bstart, rowstart, N);

        int gblocks = (int)(((size_t)N * 64 + 255) / 256);
        row_gather_kernel<<<gblocks, 256, 0, stream>>>(hbf, pairs, rowstart, out, N, E);
    } else {
        float* h = (float*)d_ws;
        hipMemsetAsync(out, 0, (size_t)out_size * sizeof(float), stream);
        gemm_kernel<<<(N + 15) / 16, 256, 0, stream>>>(x, W, bias, h, N);
        scatter_kernel<<<(E + 3) / 4, 256, 0, stream>>>(h, vals, rows, cols, out, E);
    }
}